// Round 14
// baseline (1364.907 us; speedup 1.0000x reference)
//
#include <hip/hip_runtime.h>

typedef unsigned short u16;
typedef __bf16 bf16x8 __attribute__((ext_vector_type(8)));
typedef float f32x4 __attribute__((ext_vector_type(4)));
typedef float f32x8 __attribute__((ext_vector_type(8)));
typedef unsigned short u16x8 __attribute__((ext_vector_type(8)));

#define NROWS 131072

// ---- workspace layout ----
#define OFF_SUMS   0            // [3][1024] f32
#define OFF_SQS    12288
#define OFF_PK     24576        // [1024][4] f32
#define OFF_XS     40960        // 9 f32
#define OFF_SAB    49152        // u16[1024] sa_bf16
#define OFF_SCB    53248        // u16[1024] sc_bf16
#define OFF_WT2    65536
#define OFF_WT3    (65536 + 2097152)
#define OFF_H13    8388608ull                       // h1n / h3 (256 MiB)
#define OFF_H2     (8388608ull + 268435456ull)      // h2pre (256 MiB)
#define WS_NEED    (8388608ull + 2ull * 268435456ull)   // ~520 MiB

static void* g_buf = nullptr;
__attribute__((constructor)) static void athena_alloc_buf(){
  void* p = nullptr;
  if (hipMalloc(&p, WS_NEED + (1u << 20)) == hipSuccess) g_buf = p;
  else g_buf = nullptr;
}

__device__ __forceinline__ float bf2f(u16 v){
  unsigned int u = ((unsigned int)v) << 16;
  return __builtin_bit_cast(float, u);
}
__device__ __forceinline__ u16 f2bf(float f){
  unsigned int u = __builtin_bit_cast(unsigned int, f);
  u += 0x7FFFu + ((u >> 16) & 1u);   // RNE; inputs are finite
  return (u16)(u >> 16);
}

typedef __attribute__((address_space(1))) void gvoid;
typedef __attribute__((address_space(3))) void svoid;
__device__ __forceinline__ void load_lds16(const void* g, void* l){
  __builtin_amdgcn_global_load_lds((gvoid*)g, (svoid*)l, 16, 0, 0);
}

__global__ void diag_kernel(float* out, float v){
  if (threadIdx.x == 0 && blockIdx.x == 0) out[0] = v;
}

// ---------------- W2/W3 -> bf16 transpose (Wt[n][k] = W[k][n]) ----------------
__global__ __launch_bounds__(256) void wtr_kernel(
    const float* __restrict__ W2, const float* __restrict__ W3,
    u16* __restrict__ Wt2, u16* __restrict__ Wt3)
{
  int b = blockIdx.x;
  const float* W = (b < 256) ? W2 : W3;
  u16* Wt = (b < 256) ? Wt2 : Wt3;
  b &= 255;
  const int kb = (b >> 4) * 64;
  const int n0 = (b & 15) * 64;
  __shared__ float tile[64][65];
  const int tid = threadIdx.x;
  const int tr = tid >> 4, tc = (tid & 15) * 4;
  #pragma unroll
  for (int i = 0; i < 4; i++){
    int k = tr + i * 16;
    const float* src = &W[(kb + k) * 1024 + n0 + tc];
    float4 v = *(const float4*)src;
    tile[k][tc] = v.x; tile[k][tc+1] = v.y; tile[k][tc+2] = v.z; tile[k][tc+3] = v.w;
  }
  __syncthreads();
  const int nn = tid >> 3, kc = (tid & 7) * 8;
  #pragma unroll
  for (int i = 0; i < 2; i++){
    int n = nn + i * 32;
    u16x8 o;
    #pragma unroll
    for (int j = 0; j < 8; j++) o[j] = f2bf(tile[kc + j][n]);
    *(u16x8*)&Wt[(n0 + n) * 1024 + kb + kc] = o;
  }
}

// -------- x statistics: sums and second moments (9 values) --------
__global__ __launch_bounds__(256) void xstat_kernel(
    const float* __restrict__ x, float* __restrict__ xs)
{
  const int tid = threadIdx.x;
  float s[9];
  #pragma unroll
  for (int i = 0; i < 9; i++) s[i] = 0.f;
  const int base = (blockIdx.x * 256 + tid) * 2;
  #pragma unroll
  for (int r = 0; r < 2; r++){
    const float* p = &x[(base + r) * 3];
    float a = p[0], b = p[1], c = p[2];
    s[0] += a; s[1] += b; s[2] += c;
    s[3] += a*a; s[4] += a*b; s[5] += a*c;
    s[6] += b*b; s[7] += b*c; s[8] += c*c;
  }
  #pragma unroll
  for (int i = 0; i < 9; i++){
    float v = s[i];
    #pragma unroll
    for (int off = 32; off > 0; off >>= 1) v += __shfl_xor(v, off);
    if ((tid & 63) == 0) atomicAdd(&xs[i], v);
  }
}

// -------- fold layer-1 weights + bn1 (stats derived from x-cov) into pk --------
__global__ __launch_bounds__(256) void prep_kernel(
    const float* __restrict__ W1, const float* __restrict__ b1,
    const float* __restrict__ g1, const float* __restrict__ bt1,
    const float* __restrict__ xs, float* __restrict__ pk)
{
  int k = blockIdx.x * 256 + threadIdx.x;
  if (k < 1024){
    const float inv = 1.f / 131072.f;
    float mx0 = xs[0] * inv, mx1 = xs[1] * inv, mx2 = xs[2] * inv;
    float c00 = xs[3] * inv - mx0 * mx0;
    float c01 = xs[4] * inv - mx0 * mx1;
    float c02 = xs[5] * inv - mx0 * mx2;
    float c11 = xs[6] * inv - mx1 * mx1;
    float c12 = xs[7] * inv - mx1 * mx2;
    float c22 = xs[8] * inv - mx2 * mx2;
    float w0 = W1[k], w1 = W1[1024 + k], w2 = W1[2048 + k];
    float mu  = w0 * mx0 + w1 * mx1 + w2 * mx2 + b1[k];
    float var = w0*w0*c00 + w1*w1*c11 + w2*w2*c22
              + 2.f * (w0*w1*c01 + w0*w2*c02 + w1*w2*c12);
    float a = g1[k] * rsqrtf(var + 1e-5f);
    pk[k*4+0] = a * w0;
    pk[k*4+1] = a * w1;
    pk[k*4+2] = a * w2;
    pk[k*4+3] = fmaf(a, b1[k] - mu, bt1[k]);
  }
}

// -------- finalize bn2 into bf16 sa/sc tables --------
__global__ __launch_bounds__(256) void prep2_kernel(
    const float* __restrict__ sum, const float* __restrict__ sq,
    const float* __restrict__ g, const float* __restrict__ bt,
    u16* __restrict__ sabf, u16* __restrict__ scbf)
{
  int c = blockIdx.x * 256 + threadIdx.x;
  if (c < 1024){
    float mu  = sum[c] * (1.f / 131072.f);
    float var = sq[c] * (1.f / 131072.f) - mu * mu;
    float a = g[c] * rsqrtf(var + 1e-5f);
    sabf[c] = f2bf(a);
    scbf[c] = f2bf(bt[c] - mu * a);
  }
}

// -------- materialize h1n = relu(x . pk) as bf16; cvt_pk pack stores --------
__global__ __launch_bounds__(256) void l1n_kernel(
    const float* __restrict__ x, const float* __restrict__ pk,
    u16* __restrict__ H)
{
  __shared__ float pks[1024 * 4];
  const int tid = threadIdx.x;
  for (int i = tid; i < 1024; i += 256)
    *(f32x4*)&pks[i * 4] = *(const f32x4*)&pk[i * 4];
  __syncthreads();
  const long start = (long)blockIdx.x * 256 + tid;
  const int col = (int)(start & 127) * 8;   // invariant (stride % 128 == 0)
  float p0[8], p1[8], p2[8], p3[8];
  #pragma unroll
  for (int j = 0; j < 8; j++){
    const float* p = &pks[(col + j) * 4];
    p0[j] = p[0]; p1[j] = p[1]; p2[j] = p[2]; p3[j] = p[3];
  }
  const long total = (long)131072 * 128;   // u16x8 groups
  for (long i = start; i < total; i += (long)gridDim.x * 256){
    const long row = i >> 7;
    float x0 = x[row*3+0], x1 = x[row*3+1], x2 = x[row*3+2];
    float f[8];
    #pragma unroll
    for (int j = 0; j < 8; j++){
      float t = fmaf(x0, p0[j], p3[j]);
      t = fmaf(x1, p1[j], t);
      t = fmaf(x2, p2[j], t);
      f[j] = fmaxf(t, 0.f);
    }
    unsigned int o0, o1, o2, o3;
    asm("v_cvt_pk_bf16_f32 %0, %1, %2" : "=v"(o0) : "v"(f[0]), "v"(f[1]));
    asm("v_cvt_pk_bf16_f32 %0, %1, %2" : "=v"(o1) : "v"(f[2]), "v"(f[3]));
    asm("v_cvt_pk_bf16_f32 %0, %1, %2" : "=v"(o2) : "v"(f[4]), "v"(f[5]));
    asm("v_cvt_pk_bf16_f32 %0, %1, %2" : "=v"(o3) : "v"(f[6]), "v"(f[7]));
    uint4 ov; ov.x = o0; ov.y = o1; ov.z = o2; ov.w = o3;
    *(uint4*)&H[i * 8] = ov;
  }
}

// ====== 256x256 deep-pipelined bf16 GEMM (r7 kernel, 345us measured) ======
#define STAGE(BUF, KT) do {                                                   \
    _Pragma("unroll")                                                         \
    for (int j4 = 0; j4 < 4; j4++){                                           \
      const int p = tid + j4 * 512;                                           \
      const int r = p >> 3;                                                   \
      const int q = (p & 7) ^ (r & 7);                                        \
      load_lds16(A + (m0 + r) * 1024 + ((KT) * 64 + q * 8),                   \
                 &lds[BUF][0][p * 8]);                                        \
    }                                                                         \
    _Pragma("unroll")                                                         \
    for (int j4 = 0; j4 < 4; j4++){                                           \
      const int p = tid + j4 * 512;                                           \
      const int r = p >> 3;                                                   \
      const int q = (p & 7) ^ (r & 7);                                        \
      load_lds16(Wt + (long)(n0 + r) * 1024 + ((KT) * 64 + q * 8),            \
                 &lds[BUF][1][p * 8]);                                        \
    }                                                                         \
  } while (0)

__global__ __launch_bounds__(512) void gemm_kernel(
    const u16* __restrict__ A, const u16* __restrict__ Wt,
    const float* __restrict__ bias,
    u16* __restrict__ Hout,
    float* __restrict__ osum, float* __restrict__ osq)
{
  __shared__ alignas(16) u16 lds[2][2][16384];   // [buf][A/B][256*64]
  const int tid  = threadIdx.x;
  const int lane = tid & 63;
  const int wid  = tid >> 6;
  const int fr = lane & 15;
  const int kq = lane >> 4;
  const int f7 = fr & 7;

  const int cpx  = (int)(gridDim.x >> 3);
  const int tile = ((int)blockIdx.x & 7) * cpx + ((int)blockIdx.x >> 3);
  const int tm = tile >> 2, tn = tile & 3;
  const long m0 = (long)tm * 256;
  const int  n0 = tn * 256;

  const int rbase = (wid >> 2) * 128;
  const int cbase = (wid & 3) * 64;

  f32x4 acc[8][4];
  #pragma unroll
  for (int i = 0; i < 8; i++)
    #pragma unroll
    for (int j = 0; j < 4; j++) acc[i][j] = (f32x4){0.f, 0.f, 0.f, 0.f};

  STAGE(0, 0);
  STAGE(1, 1);
  asm volatile("s_waitcnt vmcnt(8)" ::: "memory");
  __builtin_amdgcn_s_barrier();

  #define KSTEP(CUR, TNEXT, DO_STAGE, VM8, BAR2) do {                         \
    const u16* la = &lds[CUR][0][0];                                          \
    const u16* lb = &lds[CUR][1][0];                                          \
    bf16x8 bfrag[8];                                                          \
    _Pragma("unroll")                                                         \
    for (int nf = 0; nf < 4; nf++)                                            \
      _Pragma("unroll")                                                       \
      for (int ks = 0; ks < 2; ks++){                                         \
        const int r = cbase + nf * 16 + fr;                                   \
        bfrag[nf*2+ks] = *(const bf16x8*)&lb[r*64 + ((ks*4+kq)^f7)*8];        \
      }                                                                       \
    bf16x8 afrag[8];                                                          \
    _Pragma("unroll")                                                         \
    for (int mf = 0; mf < 4; mf++)                                            \
      _Pragma("unroll")                                                       \
      for (int ks = 0; ks < 2; ks++){                                         \
        const int r = rbase + mf * 16 + fr;                                   \
        afrag[mf*2+ks] = *(const bf16x8*)&la[r*64 + ((ks*4+kq)^f7)*8];        \
      }                                                                       \
    _Pragma("unroll")                                                         \
    for (int mf = 0; mf < 4; mf++)                                            \
      _Pragma("unroll")                                                       \
      for (int nf = 0; nf < 4; nf++)                                          \
        _Pragma("unroll")                                                     \
        for (int ks = 0; ks < 2; ks++)                                        \
          acc[mf][nf] = __builtin_amdgcn_mfma_f32_16x16x32_bf16(              \
              afrag[mf*2+ks], bfrag[nf*2+ks], acc[mf][nf], 0, 0, 0);          \
    bf16x8 afrag2[8];                                                         \
    _Pragma("unroll")                                                         \
    for (int mf = 0; mf < 4; mf++)                                            \
      _Pragma("unroll")                                                       \
      for (int ks = 0; ks < 2; ks++){                                         \
        const int r = rbase + 64 + mf * 16 + fr;                              \
        afrag2[mf*2+ks] = *(const bf16x8*)&la[r*64 + ((ks*4+kq)^f7)*8];       \
      }                                                                       \
    asm volatile("s_waitcnt lgkmcnt(0)" ::: "memory");                        \
    __builtin_amdgcn_s_barrier();                                             \
    if (DO_STAGE) STAGE(CUR, TNEXT);                                          \
    __builtin_amdgcn_s_setprio(1);                                            \
    _Pragma("unroll")                                                         \
    for (int mf = 0; mf < 4; mf++)                                            \
      _Pragma("unroll")                                                       \
      for (int nf = 0; nf < 4; nf++)                                          \
        _Pragma("unroll")                                                     \
        for (int ks = 0; ks < 2; ks++)                                        \
          acc[mf+4][nf] = __builtin_amdgcn_mfma_f32_16x16x32_bf16(            \
              afrag2[mf*2+ks], bfrag[nf*2+ks], acc[mf+4][nf], 0, 0, 0);       \
    __builtin_amdgcn_s_setprio(0);                                            \
    if (VM8) asm volatile("s_waitcnt vmcnt(8)" ::: "memory");                 \
    else     asm volatile("s_waitcnt vmcnt(0)" ::: "memory");                 \
    if (BAR2) __builtin_amdgcn_s_barrier();                                   \
  } while (0)

  #pragma unroll 1
  for (int t = 0; t < 14; ++t){
    KSTEP(t & 1, t + 2, 1, 1, 1);
  }
  KSTEP(0, 0, 0, 0, 1);
  KSTEP(1, 0, 0, 0, 0);
  #undef KSTEP

  const int rg = kq * 4;
  #pragma unroll
  for (int nf = 0; nf < 4; nf++){
    const int col = n0 + cbase + nf * 16 + fr;
    const float bcol = bias[col];
    float s = 0.f, q = 0.f;
    #pragma unroll
    for (int mf = 0; mf < 8; mf++){
      const long row = m0 + rbase + mf * 16 + rg;
      #pragma unroll
      for (int j = 0; j < 4; j++){
        float v = acc[mf][nf][j] + bcol;
        Hout[(row + j) * 1024 + col] = f2bf(v);
        s += v; q += v * v;
      }
    }
    s += __shfl_xor(s, 16); q += __shfl_xor(q, 16);
    s += __shfl_xor(s, 32); q += __shfl_xor(q, 32);
    if (kq == 0){
      atomicAdd(&osum[col], s);
      atomicAdd(&osq[col],  q);
    }
  }
}

// ====== gemm3 with BN2+relu fused into A-staging (once per element) ======
// Hout = relu(sa*A + sc) @ Wt^T + bias, + column stats. A reg-staged with the
// transform; B via global_load_lds. sa/sc indexed by SOURCE column (KT*64+q*8).
__global__ __launch_bounds__(512) void gemm_bn_kernel(
    const u16* __restrict__ A, const u16* __restrict__ Wt,
    const float* __restrict__ bias,
    const u16* __restrict__ sabf, const u16* __restrict__ scbf,
    u16* __restrict__ Hout,
    float* __restrict__ osum, float* __restrict__ osq)
{
  __shared__ alignas(16) u16 lds[2][2][16384];
  const int tid  = threadIdx.x;
  const int lane = tid & 63;
  const int wid  = tid >> 6;
  const int fr = lane & 15;
  const int kq = lane >> 4;
  const int f7 = fr & 7;

  const int cpx  = (int)(gridDim.x >> 3);
  const int tile = ((int)blockIdx.x & 7) * cpx + ((int)blockIdx.x >> 3);
  const int tm = tile >> 2, tn = tile & 3;
  const long m0 = (long)tm * 256;
  const int  n0 = tn * 256;

  const int rbase = (wid >> 2) * 128;
  const int cbase = (wid & 3) * 64;

  // staging geometry (tile-independent)
  int rr[4], qq[4], ldso[4];
  #pragma unroll
  for (int j4 = 0; j4 < 4; j4++){
    int p = tid + j4 * 512;
    rr[j4] = p >> 3;
    qq[j4] = (p & 7) ^ (rr[j4] & 7);
    ldso[j4] = p * 8;
  }

  f32x4 acc[8][4];
  #pragma unroll
  for (int i = 0; i < 8; i++)
    #pragma unroll
    for (int j = 0; j < 4; j++) acc[i][j] = (f32x4){0.f, 0.f, 0.f, 0.f};

  uint4 av[4], sav[4], scv[4];

  #define LOADA(T) do {                                                       \
    _Pragma("unroll")                                                         \
    for (int j4 = 0; j4 < 4; j4++){                                           \
      const int sc_ = (T) * 64 + qq[j4] * 8;                                  \
      av[j4]  = *(const uint4*)(A + (m0 + rr[j4]) * 1024 + sc_);              \
      sav[j4] = *(const uint4*)(sabf + sc_);                                  \
      scv[j4] = *(const uint4*)(scbf + sc_);                                  \
    }                                                                         \
  } while (0)

  #define XWRITE(BUF) do {                                                    \
    _Pragma("unroll")                                                         \
    for (int j4 = 0; j4 < 4; j4++){                                           \
      u16x8 a8 = __builtin_bit_cast(u16x8, av[j4]);                           \
      u16x8 s8 = __builtin_bit_cast(u16x8, sav[j4]);                          \
      u16x8 c8 = __builtin_bit_cast(u16x8, scv[j4]);                          \
      float f[8];                                                             \
      _Pragma("unroll")                                                       \
      for (int j = 0; j < 8; j++)                                             \
        f[j] = fmaxf(fmaf(bf2f(s8[j]), bf2f(a8[j]), bf2f(c8[j])), 0.f);       \
      unsigned int o0, o1, o2, o3;                                            \
      asm("v_cvt_pk_bf16_f32 %0, %1, %2" : "=v"(o0) : "v"(f[0]), "v"(f[1]));  \
      asm("v_cvt_pk_bf16_f32 %0, %1, %2" : "=v"(o1) : "v"(f[2]), "v"(f[3]));  \
      asm("v_cvt_pk_bf16_f32 %0, %1, %2" : "=v"(o2) : "v"(f[4]), "v"(f[5]));  \
      asm("v_cvt_pk_bf16_f32 %0, %1, %2" : "=v"(o3) : "v"(f[6]), "v"(f[7]));  \
      uint4 ov; ov.x = o0; ov.y = o1; ov.z = o2; ov.w = o3;                   \
      *(uint4*)&lds[BUF][0][ldso[j4]] = ov;                                   \
    }                                                                         \
  } while (0)

  #define STAGE_B(BUF, KT) do {                                               \
    _Pragma("unroll")                                                         \
    for (int j4 = 0; j4 < 4; j4++){                                           \
      load_lds16(Wt + (long)(n0 + rr[j4]) * 1024 + ((KT) * 64 + qq[j4] * 8),  \
                 &lds[BUF][1][ldso[j4]]);                                     \
    }                                                                         \
  } while (0)

  // prologue: tiles 0,1 A via reg+transform, B via gload_lds
  LOADA(0); XWRITE(0);
  LOADA(1); XWRITE(1);
  STAGE_B(0, 0); STAGE_B(1, 1);
  asm volatile("s_waitcnt vmcnt(4) lgkmcnt(0)" ::: "memory");  // B0 done, writes done
  __builtin_amdgcn_s_barrier();

  // per-tile step: at mid, vmcnt(0) drains B(t+1) + A(t+2)-loads; then stage.
  #define KSTEPB(CUR, T2, DO_STAGE, BAR2) do {                                \
    const u16* la = &lds[CUR][0][0];                                          \
    const u16* lb = &lds[CUR][1][0];                                          \
    bf16x8 bfrag[8];                                                          \
    _Pragma("unroll")                                                         \
    for (int nf = 0; nf < 4; nf++)                                            \
      _Pragma("unroll")                                                       \
      for (int ks = 0; ks < 2; ks++){                                         \
        const int r = cbase + nf * 16 + fr;                                   \
        bfrag[nf*2+ks] = *(const bf16x8*)&lb[r*64 + ((ks*4+kq)^f7)*8];        \
      }                                                                       \
    bf16x8 afrag[8];                                                          \
    _Pragma("unroll")                                                         \
    for (int mf = 0; mf < 4; mf++)                                            \
      _Pragma("unroll")                                                       \
      for (int ks = 0; ks < 2; ks++){                                         \
        const int r = rbase + mf * 16 + fr;                                   \
        afrag[mf*2+ks] = *(const bf16x8*)&la[r*64 + ((ks*4+kq)^f7)*8];        \
      }                                                                       \
    _Pragma("unroll")                                                         \
    for (int mf = 0; mf < 4; mf++)                                            \
      _Pragma("unroll")                                                       \
      for (int nf = 0; nf < 4; nf++)                                          \
        _Pragma("unroll")                                                     \
        for (int ks = 0; ks < 2; ks++)                                        \
          acc[mf][nf] = __builtin_amdgcn_mfma_f32_16x16x32_bf16(              \
              afrag[mf*2+ks], bfrag[nf*2+ks], acc[mf][nf], 0, 0, 0);          \
    bf16x8 afrag2[8];                                                         \
    _Pragma("unroll")                                                         \
    for (int mf = 0; mf < 4; mf++)                                            \
      _Pragma("unroll")                                                       \
      for (int ks = 0; ks < 2; ks++){                                         \
        const int r = rbase + 64 + mf * 16 + fr;                              \
        afrag2[mf*2+ks] = *(const bf16x8*)&la[r*64 + ((ks*4+kq)^f7)*8];       \
      }                                                                       \
    asm volatile("s_waitcnt lgkmcnt(0)" ::: "memory");  /* my reads+writes */  \
    __builtin_amdgcn_s_barrier();                       /* buf[CUR] free   */  \
    asm volatile("s_waitcnt vmcnt(0)" ::: "memory");    /* B(t+1),A(t+2) in */ \
    if (DO_STAGE){                                                            \
      STAGE_B(CUR, T2);          /* issue B(t+2) first (HBM early) */         \
      XWRITE(CUR);               /* transform + write A(t+2) */               \
    }                                                                         \
    __builtin_amdgcn_s_setprio(1);                                            \
    _Pragma("unroll")                                                         \
    for (int mf = 0; mf < 4; mf++)                                            \
      _Pragma("unroll")                                                       \
      for (int nf = 0; nf < 4; nf++)                                          \
        _Pragma("unroll")                                                     \
        for (int ks = 0; ks < 2; ks++)                                        \
          acc[mf+4][nf] = __builtin_amdgcn_mfma_f32_16x16x32_bf16(            \
              afrag2[mf*2+ks], bfrag[nf*2+ks], acc[mf+4][nf], 0, 0, 0);       \
    __builtin_amdgcn_s_setprio(0);                                            \
    if (BAR2) __builtin_amdgcn_s_barrier();                                   \
  } while (0)

  #pragma unroll 1
  for (int t = 0; t < 14; ++t){
    LOADA(t + 2);                        // issue A(t+2)+sa/sc early
    asm volatile("" ::: "memory");       // pin issue before the compute body
    KSTEPB(t & 1, t + 2, 1, 1);
  }
  KSTEPB(0, 0, 0, 1);   // t = 14
  KSTEPB(1, 0, 0, 0);   // t = 15, no trailing barrier
  #undef KSTEPB
  #undef LOADA
  #undef XWRITE
  #undef STAGE_B

  const int rg = kq * 4;
  #pragma unroll
  for (int nf = 0; nf < 4; nf++){
    const int col = n0 + cbase + nf * 16 + fr;
    const float bcol = bias[col];
    float s = 0.f, q = 0.f;
    #pragma unroll
    for (int mf = 0; mf < 8; mf++){
      const long row = m0 + rbase + mf * 16 + rg;
      #pragma unroll
      for (int j = 0; j < 4; j++){
        float v = acc[mf][nf][j] + bcol;
        Hout[(row + j) * 1024 + col] = f2bf(v);
        s += v; q += v * v;
      }
    }
    s += __shfl_xor(s, 16); q += __shfl_xor(q, 16);
    s += __shfl_xor(s, 32); q += __shfl_xor(q, 32);
    if (kq == 0){
      atomicAdd(&osum[col], s);
      atomicAdd(&osq[col],  q);
    }
  }
}

// ---- fused norm3 + head over full 1024 cols + closed-form FK ----
__global__ __launch_bounds__(256) void head_kernel(
    const u16* __restrict__ H3, const float* __restrict__ sum3,
    const float* __restrict__ sq3, const float* __restrict__ g3,
    const float* __restrict__ bt3, const float* __restrict__ W4,
    const float* __restrict__ b4, float* __restrict__ out)
{
  const int tid = threadIdx.x;
  const int lane = tid & 63;
  const int wid = tid >> 6;
  const int kA = lane * 8;
  const int kB = 512 + lane * 8;
  float a[16], cc[16], w[16][3];
  #pragma unroll
  for (int h = 0; h < 2; h++){
    #pragma unroll
    for (int j = 0; j < 8; j++){
      int kg = (h ? kB : kA) + j;
      float mu  = sum3[kg] * (1.f / 131072.f);
      float var = sq3[kg] * (1.f / 131072.f) - mu * mu;
      float av = g3[kg] * rsqrtf(var + 1e-5f);
      a[h*8+j]  = av;
      cc[h*8+j] = bt3[kg] - mu * av;
      w[h*8+j][0] = W4[kg*3+0]; w[h*8+j][1] = W4[kg*3+1]; w[h*8+j][2] = W4[kg*3+2];
    }
  }
  const float bb0 = b4[0], bb1 = b4[1], bb2 = b4[2];
  const int base = blockIdx.x * 16 + wid * 4;
  for (int rr = 0; rr < 4; rr++){
    const int row = base + rr;
    u16x8 va = *(const u16x8*)&H3[(long)row * 1024 + kA];
    u16x8 vb = *(const u16x8*)&H3[(long)row * 1024 + kB];
    float t0 = 0.f, t1 = 0.f, t2 = 0.f;
    #pragma unroll
    for (int j = 0; j < 8; j++){
      float h0 = fmaxf(fmaf(a[j],   bf2f(va[j]), cc[j]),   0.f);
      t0 = fmaf(h0, w[j][0], t0); t1 = fmaf(h0, w[j][1], t1); t2 = fmaf(h0, w[j][2], t2);
      float h1 = fmaxf(fmaf(a[8+j], bf2f(vb[j]), cc[8+j]), 0.f);
      t0 = fmaf(h1, w[8+j][0], t0); t1 = fmaf(h1, w[8+j][1], t1); t2 = fmaf(h1, w[8+j][2], t2);
    }
    #pragma unroll
    for (int off = 32; off > 0; off >>= 1){
      t0 += __shfl_xor(t0, off);
      t1 += __shfl_xor(t1, off);
      t2 += __shfl_xor(t2, off);
    }
    if (lane == 0){
      t0 += bb0; t1 += bb1; t2 += bb2;
      out[row*3+0] = t0; out[row*3+1] = t1; out[row*3+2] = t2;
      float c0s = cosf(t0), s0s = sinf(t0);
      float c1s = cosf(t1), s1s = sinf(t1);
      float t12 = t1 + t2;
      float c12 = cosf(t12), s12 = sinf(t12);
      float L = 0.12f * c1s + 0.115f * c12;
      float* p = out + (long)131072 * 3 + (long)row * 3;
      p[0] = c0s * L; p[1] = s0s * L; p[2] = 0.12f * s1s + 0.115f * s12;
    }
  }
}

extern "C" void kernel_launch(void* const* d_in, const int* in_sizes, int n_in,
                              void* d_out, int out_size, void* d_ws, size_t ws_size,
                              hipStream_t stream)
{
  (void)in_sizes; (void)n_in; (void)out_size;
  const float* x   = (const float*)d_in[0];
  const float* W1  = (const float*)d_in[1];
  const float* b1  = (const float*)d_in[2];
  const float* g1  = (const float*)d_in[3];
  const float* bt1 = (const float*)d_in[4];
  const float* W2  = (const float*)d_in[5];
  const float* b2  = (const float*)d_in[6];
  const float* g2  = (const float*)d_in[7];
  const float* bt2 = (const float*)d_in[8];
  const float* W3  = (const float*)d_in[9];
  const float* b3  = (const float*)d_in[10];
  const float* g3  = (const float*)d_in[11];
  const float* bt3 = (const float*)d_in[12];
  const float* W4  = (const float*)d_in[13];
  const float* b4  = (const float*)d_in[14];
  float* out = (float*)d_out;

  char* base = nullptr;
  if (ws_size >= WS_NEED) base = (char*)d_ws;
  else if (g_buf)         base = (char*)g_buf;
  if (!base){
    diag_kernel<<<1, 64, 0, stream>>>(out, 10000.0f + (float)(ws_size >> 20));
    return;
  }

  float* sums = (float*)(base + OFF_SUMS);
  float* sqs  = (float*)(base + OFF_SQS);
  float* pk   = (float*)(base + OFF_PK);
  float* xs   = (float*)(base + OFF_XS);
  u16* sabf = (u16*)(base + OFF_SAB);
  u16* scbf = (u16*)(base + OFF_SCB);
  u16* Wt2 = (u16*)(base + OFF_WT2);
  u16* Wt3 = (u16*)(base + OFF_WT3);
  u16* hA  = (u16*)(base + OFF_H13);         // h1n, then h3
  u16* hB  = (u16*)(base + OFF_H2);          // h2pre

  hipMemsetAsync(base, 0, 48 * 1024, stream);
  wtr_kernel   <<<512,  256, 0, stream>>>(W2, W3, Wt2, Wt3);
  xstat_kernel <<<256,  256, 0, stream>>>(x, xs);
  prep_kernel  <<<4,    256, 0, stream>>>(W1, b1, g1, bt1, xs, pk);
  l1n_kernel   <<<2048, 256, 0, stream>>>(x, pk, hA);                // hA = h1n
  gemm_kernel  <<<2048, 512, 0, stream>>>(hA, Wt2, b2, hB,           // hB = h2pre
                                          sums + 1024, sqs + 1024);
  prep2_kernel <<<4,    256, 0, stream>>>(sums + 1024, sqs + 1024, g2, bt2,
                                          sabf, scbf);
  gemm_bn_kernel<<<2048, 512, 0, stream>>>(hB, Wt3, b3, sabf, scbf, hA,  // hA = h3
                                           sums + 2048, sqs + 2048);
  head_kernel  <<<8192, 256, 0, stream>>>(hA, sums + 2048, sqs + 2048, g3, bt3,
                                          W4, b4, out);
}

// Round 15
// 1017.658 us; speedup vs baseline: 1.3412x; 1.3412x over previous
//
#include <hip/hip_runtime.h>

typedef unsigned short u16;
typedef __bf16 bf16x8 __attribute__((ext_vector_type(8)));
typedef float f32x4 __attribute__((ext_vector_type(4)));
typedef float f32x8 __attribute__((ext_vector_type(8)));
typedef unsigned short u16x8 __attribute__((ext_vector_type(8)));

#define NROWS 131072

// ---- workspace layout ----
#define OFF_SUMS   0            // [3][1024] f32
#define OFF_SQS    12288
#define OFF_XS     40960        // 9 f32
#define OFF_WT2    65536
#define OFF_WT3    (65536 + 2097152)
#define OFF_H13    8388608ull                       // h1n / h2n (256 MiB)
#define OFF_H2     (8388608ull + 268435456ull)      // h2pre / h3 (256 MiB)
#define WS_NEED    (8388608ull + 2ull * 268435456ull)   // ~520 MiB

static void* g_buf = nullptr;
__attribute__((constructor)) static void athena_alloc_buf(){
  void* p = nullptr;
  if (hipMalloc(&p, WS_NEED + (1u << 20)) == hipSuccess) g_buf = p;
  else g_buf = nullptr;
}

__device__ __forceinline__ float bf2f(u16 v){
  unsigned int u = ((unsigned int)v) << 16;
  return __builtin_bit_cast(float, u);
}
__device__ __forceinline__ u16 f2bf(float f){
  unsigned int u = __builtin_bit_cast(unsigned int, f);
  u += 0x7FFFu + ((u >> 16) & 1u);   // RNE; inputs are finite
  return (u16)(u >> 16);
}

typedef __attribute__((address_space(1))) void gvoid;
typedef __attribute__((address_space(3))) void svoid;
__device__ __forceinline__ void load_lds16(const void* g, void* l){
  __builtin_amdgcn_global_load_lds((gvoid*)g, (svoid*)l, 16, 0, 0);
}

__global__ void diag_kernel(float* out, float v){
  if (threadIdx.x == 0 && blockIdx.x == 0) out[0] = v;
}

// ---- merged: W2/W3 -> bf16 transpose (blocks 0..511) + x stats (512..767) ----
__global__ __launch_bounds__(256) void wx_kernel(
    const float* __restrict__ W2, const float* __restrict__ W3,
    u16* __restrict__ Wt2, u16* __restrict__ Wt3,
    const float* __restrict__ x, float* __restrict__ xs)
{
  const int tid = threadIdx.x;
  if (blockIdx.x < 512){
    int b = blockIdx.x;
    const float* W = (b < 256) ? W2 : W3;
    u16* Wt = (b < 256) ? Wt2 : Wt3;
    b &= 255;
    const int kb = (b >> 4) * 64;
    const int n0 = (b & 15) * 64;
    __shared__ float tile[64][65];
    const int tr = tid >> 4, tc = (tid & 15) * 4;
    #pragma unroll
    for (int i = 0; i < 4; i++){
      int k = tr + i * 16;
      const float* src = &W[(kb + k) * 1024 + n0 + tc];
      float4 v = *(const float4*)src;
      tile[k][tc] = v.x; tile[k][tc+1] = v.y; tile[k][tc+2] = v.z; tile[k][tc+3] = v.w;
    }
    __syncthreads();
    const int nn = tid >> 3, kc = (tid & 7) * 8;
    #pragma unroll
    for (int i = 0; i < 2; i++){
      int n = nn + i * 32;
      u16x8 o;
      #pragma unroll
      for (int j = 0; j < 8; j++) o[j] = f2bf(tile[kc + j][n]);
      *(u16x8*)&Wt[(n0 + n) * 1024 + kb + kc] = o;
    }
  } else {
    float s[9];
    #pragma unroll
    for (int i = 0; i < 9; i++) s[i] = 0.f;
    const int base = (((int)blockIdx.x - 512) * 256 + tid) * 2;
    #pragma unroll
    for (int r = 0; r < 2; r++){
      const float* p = &x[(base + r) * 3];
      float a = p[0], b = p[1], c = p[2];
      s[0] += a; s[1] += b; s[2] += c;
      s[3] += a*a; s[4] += a*b; s[5] += a*c;
      s[6] += b*b; s[7] += b*c; s[8] += c*c;
    }
    #pragma unroll
    for (int i = 0; i < 9; i++){
      float v = s[i];
      #pragma unroll
      for (int off = 32; off > 0; off >>= 1) v += __shfl_xor(v, off);
      if ((tid & 63) == 0) atomicAdd(&xs[i], v);
    }
  }
}

// -------- h1n = relu(bn1(x@W1+b1)) as bf16; pk folded in-kernel --------
// bn1 stats derived analytically from x covariance (xs): mu_h = w.mx + b,
// var_h = w^T Cov(x) w -- exact since layer 1 is linear in x.
__global__ __launch_bounds__(256) void l1n_kernel(
    const float* __restrict__ x,
    const float* __restrict__ W1, const float* __restrict__ b1,
    const float* __restrict__ g1, const float* __restrict__ bt1,
    const float* __restrict__ xs, u16* __restrict__ H)
{
  const int tid = threadIdx.x;
  const long start = (long)blockIdx.x * 256 + tid;
  const int col = (int)(start & 127) * 8;   // invariant (stride % 128 == 0)
  const float inv = 1.f / 131072.f;
  const float mx0 = xs[0] * inv, mx1 = xs[1] * inv, mx2 = xs[2] * inv;
  const float c00 = xs[3] * inv - mx0 * mx0;
  const float c01 = xs[4] * inv - mx0 * mx1;
  const float c02 = xs[5] * inv - mx0 * mx2;
  const float c11 = xs[6] * inv - mx1 * mx1;
  const float c12 = xs[7] * inv - mx1 * mx2;
  const float c22 = xs[8] * inv - mx2 * mx2;
  float p0[8], p1[8], p2[8], p3[8];
  #pragma unroll
  for (int j = 0; j < 8; j++){
    const int k = col + j;
    float w0 = W1[k], w1 = W1[1024 + k], w2 = W1[2048 + k];
    float mu  = w0 * mx0 + w1 * mx1 + w2 * mx2 + b1[k];
    float var = w0*w0*c00 + w1*w1*c11 + w2*w2*c22
              + 2.f * (w0*w1*c01 + w0*w2*c02 + w1*w2*c12);
    float a = g1[k] * rsqrtf(var + 1e-5f);
    p0[j] = a * w0; p1[j] = a * w1; p2[j] = a * w2;
    p3[j] = fmaf(a, b1[k] - mu, bt1[k]);
  }
  const long total = (long)131072 * 128;   // u16x8 groups
  for (long i = start; i < total; i += (long)gridDim.x * 256){
    const long row = i >> 7;
    float x0 = x[row*3+0], x1 = x[row*3+1], x2 = x[row*3+2];
    float f[8];
    #pragma unroll
    for (int j = 0; j < 8; j++){
      float t = fmaf(x0, p0[j], p3[j]);
      t = fmaf(x1, p1[j], t);
      t = fmaf(x2, p2[j], t);
      f[j] = fmaxf(t, 0.f);
    }
    unsigned int o0, o1, o2, o3;
    asm("v_cvt_pk_bf16_f32 %0, %1, %2" : "=v"(o0) : "v"(f[0]), "v"(f[1]));
    asm("v_cvt_pk_bf16_f32 %0, %1, %2" : "=v"(o1) : "v"(f[2]), "v"(f[3]));
    asm("v_cvt_pk_bf16_f32 %0, %1, %2" : "=v"(o2) : "v"(f[4]), "v"(f[5]));
    asm("v_cvt_pk_bf16_f32 %0, %1, %2" : "=v"(o3) : "v"(f[6]), "v"(f[7]));
    uint4 ov; ov.x = o0; ov.y = o1; ov.z = o2; ov.w = o3;
    *(uint4*)&H[i * 8] = ov;
  }
}

// ====== 256x256 deep-pipelined bf16 GEMM (r7 kernel, 345us measured) ======
// T1 XCD swizzle + T2 both-sides XOR swizzle (conflicts=0) + counted vmcnt(8)
// + setprio around the staging-overlapped MFMA batch. Direct-store epilogue
// with fused bias + column sum/sumsq atomics (write-amp accepted: not BW-bound).

#define STAGE(BUF, KT) do {                                                   \
    _Pragma("unroll")                                                         \
    for (int j4 = 0; j4 < 4; j4++){                                           \
      const int p = tid + j4 * 512;                                           \
      const int r = p >> 3;                                                   \
      const int q = (p & 7) ^ (r & 7);                                        \
      load_lds16(A + (m0 + r) * 1024 + ((KT) * 64 + q * 8),                   \
                 &lds[BUF][0][p * 8]);                                        \
    }                                                                         \
    _Pragma("unroll")                                                         \
    for (int j4 = 0; j4 < 4; j4++){                                           \
      const int p = tid + j4 * 512;                                           \
      const int r = p >> 3;                                                   \
      const int q = (p & 7) ^ (r & 7);                                        \
      load_lds16(Wt + (long)(n0 + r) * 1024 + ((KT) * 64 + q * 8),            \
                 &lds[BUF][1][p * 8]);                                        \
    }                                                                         \
  } while (0)

__global__ __launch_bounds__(512) void gemm_kernel(
    const u16* __restrict__ A, const u16* __restrict__ Wt,
    const float* __restrict__ bias,
    u16* __restrict__ Hout,
    float* __restrict__ osum, float* __restrict__ osq)
{
  __shared__ alignas(16) u16 lds[2][2][16384];   // [buf][A/B][256*64]
  const int tid  = threadIdx.x;
  const int lane = tid & 63;
  const int wid  = tid >> 6;
  const int fr = lane & 15;
  const int kq = lane >> 4;
  const int f7 = fr & 7;

  const int cpx  = (int)(gridDim.x >> 3);
  const int tile = ((int)blockIdx.x & 7) * cpx + ((int)blockIdx.x >> 3);
  const int tm = tile >> 2, tn = tile & 3;
  const long m0 = (long)tm * 256;
  const int  n0 = tn * 256;

  const int rbase = (wid >> 2) * 128;
  const int cbase = (wid & 3) * 64;

  f32x4 acc[8][4];
  #pragma unroll
  for (int i = 0; i < 8; i++)
    #pragma unroll
    for (int j = 0; j < 4; j++) acc[i][j] = (f32x4){0.f, 0.f, 0.f, 0.f};

  STAGE(0, 0);
  STAGE(1, 1);
  asm volatile("s_waitcnt vmcnt(8)" ::: "memory");
  __builtin_amdgcn_s_barrier();

  #define KSTEP(CUR, TNEXT, DO_STAGE, VM8, BAR2) do {                         \
    const u16* la = &lds[CUR][0][0];                                          \
    const u16* lb = &lds[CUR][1][0];                                          \
    bf16x8 bfrag[8];                                                          \
    _Pragma("unroll")                                                         \
    for (int nf = 0; nf < 4; nf++)                                            \
      _Pragma("unroll")                                                       \
      for (int ks = 0; ks < 2; ks++){                                         \
        const int r = cbase + nf * 16 + fr;                                   \
        bfrag[nf*2+ks] = *(const bf16x8*)&lb[r*64 + ((ks*4+kq)^f7)*8];        \
      }                                                                       \
    bf16x8 afrag[8];                                                          \
    _Pragma("unroll")                                                         \
    for (int mf = 0; mf < 4; mf++)                                            \
      _Pragma("unroll")                                                       \
      for (int ks = 0; ks < 2; ks++){                                         \
        const int r = rbase + mf * 16 + fr;                                   \
        afrag[mf*2+ks] = *(const bf16x8*)&la[r*64 + ((ks*4+kq)^f7)*8];        \
      }                                                                       \
    _Pragma("unroll")                                                         \
    for (int mf = 0; mf < 4; mf++)                                            \
      _Pragma("unroll")                                                       \
      for (int nf = 0; nf < 4; nf++)                                          \
        _Pragma("unroll")                                                     \
        for (int ks = 0; ks < 2; ks++)                                        \
          acc[mf][nf] = __builtin_amdgcn_mfma_f32_16x16x32_bf16(              \
              afrag[mf*2+ks], bfrag[nf*2+ks], acc[mf][nf], 0, 0, 0);          \
    bf16x8 afrag2[8];                                                         \
    _Pragma("unroll")                                                         \
    for (int mf = 0; mf < 4; mf++)                                            \
      _Pragma("unroll")                                                       \
      for (int ks = 0; ks < 2; ks++){                                         \
        const int r = rbase + 64 + mf * 16 + fr;                              \
        afrag2[mf*2+ks] = *(const bf16x8*)&la[r*64 + ((ks*4+kq)^f7)*8];       \
      }                                                                       \
    asm volatile("s_waitcnt lgkmcnt(0)" ::: "memory");                        \
    __builtin_amdgcn_s_barrier();                                             \
    if (DO_STAGE) STAGE(CUR, TNEXT);                                          \
    __builtin_amdgcn_s_setprio(1);                                            \
    _Pragma("unroll")                                                         \
    for (int mf = 0; mf < 4; mf++)                                            \
      _Pragma("unroll")                                                       \
      for (int nf = 0; nf < 4; nf++)                                          \
        _Pragma("unroll")                                                     \
        for (int ks = 0; ks < 2; ks++)                                        \
          acc[mf+4][nf] = __builtin_amdgcn_mfma_f32_16x16x32_bf16(            \
              afrag2[mf*2+ks], bfrag[nf*2+ks], acc[mf+4][nf], 0, 0, 0);       \
    __builtin_amdgcn_s_setprio(0);                                            \
    if (VM8) asm volatile("s_waitcnt vmcnt(8)" ::: "memory");                 \
    else     asm volatile("s_waitcnt vmcnt(0)" ::: "memory");                 \
    if (BAR2) __builtin_amdgcn_s_barrier();                                   \
  } while (0)

  #pragma unroll 1
  for (int t = 0; t < 14; ++t){
    KSTEP(t & 1, t + 2, 1, 1, 1);
  }
  KSTEP(0, 0, 0, 0, 1);
  KSTEP(1, 0, 0, 0, 0);
  #undef KSTEP

  const int rg = kq * 4;
  #pragma unroll
  for (int nf = 0; nf < 4; nf++){
    const int col = n0 + cbase + nf * 16 + fr;
    const float bcol = bias[col];
    float s = 0.f, q = 0.f;
    #pragma unroll
    for (int mf = 0; mf < 8; mf++){
      const long row = m0 + rbase + mf * 16 + rg;
      #pragma unroll
      for (int j = 0; j < 4; j++){
        float v = acc[mf][nf][j] + bcol;
        Hout[(row + j) * 1024 + col] = f2bf(v);
        s += v; q += v * v;
      }
    }
    s += __shfl_xor(s, 16); q += __shfl_xor(q, 16);
    s += __shfl_xor(s, 32); q += __shfl_xor(q, 32);
    if (kq == 0){
      atomicAdd(&osum[col], s);
      atomicAdd(&osq[col],  q);
    }
  }
}

// ------- normalize pass: Hn = relu(a*Hpre + c), out-of-place, cvt_pk -------
__global__ __launch_bounds__(256) void norm_kernel(
    const u16* __restrict__ Hpre, u16* __restrict__ Hn,
    const float* __restrict__ sum, const float* __restrict__ sq,
    const float* __restrict__ g, const float* __restrict__ bt)
{
  __shared__ float sa[1024], sc[1024];
  const int tid = threadIdx.x;
  for (int c = tid; c < 1024; c += 256){
    float mu  = sum[c] * (1.f / 131072.f);
    float var = sq[c] * (1.f / 131072.f) - mu * mu;
    float a = g[c] * rsqrtf(var + 1e-5f);
    sa[c] = a; sc[c] = bt[c] - mu * a;
  }
  __syncthreads();
  const long start = (long)blockIdx.x * 256 + tid;
  const int col = (int)(start & 127) * 8;   // invariant (stride % 128 == 0)
  float ar[8], cr[8];
  #pragma unroll
  for (int j = 0; j < 8; j++){ ar[j] = sa[col + j]; cr[j] = sc[col + j]; }
  const long total = (long)131072 * 128;
  for (long i = start; i < total; i += (long)gridDim.x * 256){
    u16x8 v = *(const u16x8*)&Hpre[i * 8];
    float f[8];
    #pragma unroll
    for (int j = 0; j < 8; j++){
      unsigned int u = ((unsigned int)v[j]) << 16;
      f[j] = fmaxf(fmaf(ar[j], __builtin_bit_cast(float, u), cr[j]), 0.f);
    }
    unsigned int o0, o1, o2, o3;
    asm("v_cvt_pk_bf16_f32 %0, %1, %2" : "=v"(o0) : "v"(f[0]), "v"(f[1]));
    asm("v_cvt_pk_bf16_f32 %0, %1, %2" : "=v"(o1) : "v"(f[2]), "v"(f[3]));
    asm("v_cvt_pk_bf16_f32 %0, %1, %2" : "=v"(o2) : "v"(f[4]), "v"(f[5]));
    asm("v_cvt_pk_bf16_f32 %0, %1, %2" : "=v"(o3) : "v"(f[6]), "v"(f[7]));
    uint4 ov; ov.x = o0; ov.y = o1; ov.z = o2; ov.w = o3;
    *(uint4*)&Hn[i * 8] = ov;
  }
}

// ---- fused norm3 + head over full 1024 cols + closed-form FK ----
__global__ __launch_bounds__(256) void head_kernel(
    const u16* __restrict__ H3, const float* __restrict__ sum3,
    const float* __restrict__ sq3, const float* __restrict__ g3,
    const float* __restrict__ bt3, const float* __restrict__ W4,
    const float* __restrict__ b4, float* __restrict__ out)
{
  const int tid = threadIdx.x;
  const int lane = tid & 63;
  const int wid = tid >> 6;
  const int kA = lane * 8;
  const int kB = 512 + lane * 8;
  float a[16], cc[16], w[16][3];
  #pragma unroll
  for (int h = 0; h < 2; h++){
    #pragma unroll
    for (int j = 0; j < 8; j++){
      int kg = (h ? kB : kA) + j;
      float mu  = sum3[kg] * (1.f / 131072.f);
      float var = sq3[kg] * (1.f / 131072.f) - mu * mu;
      float av = g3[kg] * rsqrtf(var + 1e-5f);
      a[h*8+j]  = av;
      cc[h*8+j] = bt3[kg] - mu * av;
      w[h*8+j][0] = W4[kg*3+0]; w[h*8+j][1] = W4[kg*3+1]; w[h*8+j][2] = W4[kg*3+2];
    }
  }
  const float bb0 = b4[0], bb1 = b4[1], bb2 = b4[2];
  const int base = blockIdx.x * 16 + wid * 4;
  for (int rr = 0; rr < 4; rr++){
    const int row = base + rr;
    u16x8 va = *(const u16x8*)&H3[(long)row * 1024 + kA];
    u16x8 vb = *(const u16x8*)&H3[(long)row * 1024 + kB];
    float t0 = 0.f, t1 = 0.f, t2 = 0.f;
    #pragma unroll
    for (int j = 0; j < 8; j++){
      float h0 = fmaxf(fmaf(a[j],   bf2f(va[j]), cc[j]),   0.f);
      t0 = fmaf(h0, w[j][0], t0); t1 = fmaf(h0, w[j][1], t1); t2 = fmaf(h0, w[j][2], t2);
      float h1 = fmaxf(fmaf(a[8+j], bf2f(vb[j]), cc[8+j]), 0.f);
      t0 = fmaf(h1, w[8+j][0], t0); t1 = fmaf(h1, w[8+j][1], t1); t2 = fmaf(h1, w[8+j][2], t2);
    }
    #pragma unroll
    for (int off = 32; off > 0; off >>= 1){
      t0 += __shfl_xor(t0, off);
      t1 += __shfl_xor(t1, off);
      t2 += __shfl_xor(t2, off);
    }
    if (lane == 0){
      t0 += bb0; t1 += bb1; t2 += bb2;
      out[row*3+0] = t0; out[row*3+1] = t1; out[row*3+2] = t2;
      float c0s = cosf(t0), s0s = sinf(t0);
      float c1s = cosf(t1), s1s = sinf(t1);
      float t12 = t1 + t2;
      float c12 = cosf(t12), s12 = sinf(t12);
      float L = 0.12f * c1s + 0.115f * c12;
      float* p = out + (long)131072 * 3 + (long)row * 3;
      p[0] = c0s * L; p[1] = s0s * L; p[2] = 0.12f * s1s + 0.115f * s12;
    }
  }
}

extern "C" void kernel_launch(void* const* d_in, const int* in_sizes, int n_in,
                              void* d_out, int out_size, void* d_ws, size_t ws_size,
                              hipStream_t stream)
{
  (void)in_sizes; (void)n_in; (void)out_size;
  const float* x   = (const float*)d_in[0];
  const float* W1  = (const float*)d_in[1];
  const float* b1  = (const float*)d_in[2];
  const float* g1  = (const float*)d_in[3];
  const float* bt1 = (const float*)d_in[4];
  const float* W2  = (const float*)d_in[5];
  const float* b2  = (const float*)d_in[6];
  const float* g2  = (const float*)d_in[7];
  const float* bt2 = (const float*)d_in[8];
  const float* W3  = (const float*)d_in[9];
  const float* b3  = (const float*)d_in[10];
  const float* g3  = (const float*)d_in[11];
  const float* bt3 = (const float*)d_in[12];
  const float* W4  = (const float*)d_in[13];
  const float* b4  = (const float*)d_in[14];
  float* out = (float*)d_out;

  char* base = nullptr;
  if (ws_size >= WS_NEED) base = (char*)d_ws;
  else if (g_buf)         base = (char*)g_buf;
  if (!base){
    diag_kernel<<<1, 64, 0, stream>>>(out, 10000.0f + (float)(ws_size >> 20));
    return;
  }

  float* sums = (float*)(base + OFF_SUMS);
  float* sqs  = (float*)(base + OFF_SQS);
  float* xs   = (float*)(base + OFF_XS);
  u16* Wt2 = (u16*)(base + OFF_WT2);
  u16* Wt3 = (u16*)(base + OFF_WT3);
  u16* hA  = (u16*)(base + OFF_H13);         // h1n, then h2n
  u16* hB  = (u16*)(base + OFF_H2);          // h2pre, then h3

  hipMemsetAsync(base, 0, 48 * 1024, stream);
  wx_kernel   <<<768,  256, 0, stream>>>(W2, W3, Wt2, Wt3, x, xs);
  l1n_kernel  <<<2048, 256, 0, stream>>>(x, W1, b1, g1, bt1, xs, hA);   // hA = h1n
  gemm_kernel <<<2048, 512, 0, stream>>>(hA, Wt2, b2, hB,               // hB = h2pre
                                         sums + 1024, sqs + 1024);
  norm_kernel <<<2048, 256, 0, stream>>>(hB, hA,                        // hA = h2n
                                         sums + 1024, sqs + 1024, g2, bt2);
  gemm_kernel <<<2048, 512, 0, stream>>>(hA, Wt3, b3, hB,               // hB = h3pre
                                         sums + 2048, sqs + 2048);
  head_kernel <<<8192, 256, 0, stream>>>(hB, sums + 2048, sqs + 2048, g3, bt3,
                                         W4, b4, out);
}